// Round 20
// baseline (355.640 us; speedup 1.0000x reference)
//
#include <hip/hip_runtime.h>
#include <math.h>

#define SD 7
#define HID 64
#define NITER 10

typedef float f16s __attribute__((ext_vector_type(16)));
typedef float f8s  __attribute__((ext_vector_type(8)));
typedef float f2   __attribute__((ext_vector_type(2)));

#define REP7(M)  M(0) M(1) M(2) M(3) M(4) M(5) M(6)
#define AP8(M, ...) M(0, __VA_ARGS__) M(1, __VA_ARGS__) M(2, __VA_ARGS__) M(3, __VA_ARGS__) \
    M(4, __VA_ARGS__) M(5, __VA_ARGS__) M(6, __VA_ARGS__) M(7, __VA_ARGS__)

// ---- SMEM loads (volatile => never hoisted) ----
#define SLOAD4(d0, d1, d2, d3, p, o0, o1, o2, o3) \
    asm volatile("s_load_dwordx16 %0, %4, %5\n\t" \
                 "s_load_dwordx16 %1, %4, %6\n\t" \
                 "s_load_dwordx16 %2, %4, %7\n\t" \
                 "s_load_dwordx16 %3, %4, %8\n\t" \
                 "s_waitcnt lgkmcnt(0)" \
                 : "=&s"(d0), "=&s"(d1), "=&s"(d2), "=&s"(d3) \
                 : "s"(p), "i"(o0), "i"(o1), "i"(o2), "i"(o3));

#define SLOADX8(d0, p) \
    asm volatile("s_load_dwordx8 %0, %1, 0\n\t" \
                 "s_waitcnt lgkmcnt(0)" \
                 : "=&s"(d0) : "s"(p));

// ---- pair extracts (plain values; fold into VOP3P scalar operand) ----
#define PKW(W, e)   __builtin_shufflevector((W), (W), 2*(e), 2*(e)+1)   // f16s -> f2

// ---- plain C packed math (clang -> v_pk_* on gfx950) ----
#define PKFMA_ACC(acc, w2, m2)      (acc) = __builtin_elementwise_fma((w2), (m2), (acc));
#define PKFMA_NEW(dst, w2, m2, c2)  (dst) = __builtin_elementwise_fma((w2), (m2), (c2));

#define PKROW_E(e, arr, base, m2v, W) PKFMA_ACC((arr)[(base)+(e)], PKW(W, e), m2v)
#define PKROW(arr, m2v, wa, wb, wc, wd) \
    AP8(PKROW_E, arr, 0,  m2v, wa) AP8(PKROW_E, arr, 8,  m2v, wb) \
    AP8(PKROW_E, arr, 16, m2v, wc) AP8(PKROW_E, arr, 24, m2v, wd)

// out-matmul partial: accX += owT-pair * xe2[pair]
#define OPK_E(e, acc, base, W) PKFMA_ACC(acc, PKW(W, e), xe2[(base)+(e)])

// prep: owT[7][64] transpose + interleaved ln params {ls0,ls1,lb0,lb1,...}
__global__ void prep_kernel(const float* __restrict__ ow,
                            const float* __restrict__ lns,
                            const float* __restrict__ lnb,
                            float* __restrict__ ws) {
    int t = threadIdx.x;
    if (t < HID * SD) {
        ws[(t % SD) * HID + (t / SD)] = ow[t];            // owT[i][j]
    } else if (t < HID * SD + 2 * HID) {
        int i = t - HID * SD;                             // 0..127
        int p = i >> 2, r = i & 3;
        ws[HID * SD + i] = (r < 2) ? lns[2 * p + r] : lnb[2 * p + (r - 2)];
    }
}

__global__ __launch_bounds__(256) __attribute__((amdgpu_waves_per_eu(3, 3)))
void strange_loop_kernel(const float* __restrict__ s7,
                         const float* __restrict__ w0,
                         const float* __restrict__ b0,
                         const float* __restrict__ owt,
                         const float* __restrict__ lsb,
                         const float* __restrict__ ob,
                         float* __restrict__ out_mu,
                         float* __restrict__ out_cv,
                         int Bn)
{
    const int tid = threadIdx.x;
    int row = blockIdx.x * blockDim.x + tid;
    if (row >= Bn) row = Bn - 1;   // clamp: uniform control flow, dup write benign

    float s[SD];
#define LD_S(k) s[k] = s7[(size_t)row * SD + (k)];
    REP7(LD_S)

    // ---- iteration-invariant: Be2 = b0 + sum_k s[k]*W0[7+k][.] (packed pairs) ----
    f2 Be2[32];
    {
        f16s ba, bb, bc, bd;
        SLOAD4(ba, bb, bc, bd, b0, 0, 64, 128, 192)
#define B0P(e, W, base) Be2[(base)+(e)] = PKW(W, e);
        AP8(B0P, ba, 0) AP8(B0P, bb, 8) AP8(B0P, bc, 16) AP8(B0P, bd, 24)
    }
#define BIK(k) { f16s wa, wb, wc, wd; \
    SLOAD4(wa, wb, wc, wd, w0, (7+(k))*256, (7+(k))*256+64, (7+(k))*256+128, (7+(k))*256+192) \
    f2 m2 = {s[k], s[k]}; \
    PKROW(Be2, m2, wa, wb, wc, wd) }
    REP7(BIK)

    f8s obv;
    SLOADX8(obv, ob)

    float mu[SD];
#define INITMU(i) mu[i] = 0.37796447300922720f;   // 1/sqrt(7)
    REP7(INITMU)
    float conv = 0.0f;

    // GELU constants, log2e pre-folded (double-folded at compile time):
    // e^(kC*(g + kB g^3)) == 2^( g * (kCl + kBCl*g^2) )
    const double kCd  = -1.5957691216057308 * 1.4426950408889634;
    const float  kCl  = (float)kCd;
    const float  kBCl = (float)(kCd * 0.044715);

#pragma unroll 1
    for (int it = 0; it < NITER; ++it) {
        // ---- fc0 packed: xe2 = Be2 + sum_k mu[k]*W0[k][.]; k=0 writes fresh ----
        f2 xe2[32];
        { f16s wa, wb, wc, wd;
          SLOAD4(wa, wb, wc, wd, w0, 0, 64, 128, 192)
          f2 m2 = {mu[0], mu[0]};
#define FC00_E(e, W, base) PKFMA_NEW(xe2[(base)+(e)], PKW(W, e), m2, Be2[(base)+(e)])
          AP8(FC00_E, wa, 0) AP8(FC00_E, wb, 8) AP8(FC00_E, wc, 16) AP8(FC00_E, wd, 24)
        }
#define FC0K(k) { f16s wa, wb, wc, wd; \
        SLOAD4(wa, wb, wc, wd, w0, (k)*256, (k)*256+64, (k)*256+128, (k)*256+192) \
        f2 m2 = {mu[k], mu[k]}; \
        PKROW(xe2, m2, wa, wb, wc, wd) }
        FC0K(1) FC0K(2) FC0K(3) FC0K(4) FC0K(5) FC0K(6)

        // ---- LayerNorm one-pass, 4-way split chains (7-deep) + tree combine ----
        f2 S0 = xe2[0], S1 = xe2[8], S2 = xe2[16], S3 = xe2[24];
        f2 Q0 = xe2[0] * xe2[0], Q1 = xe2[8] * xe2[8];
        f2 Q2 = xe2[16] * xe2[16], Q3 = xe2[24] * xe2[24];
#define LNE(j) { \
        S0 += xe2[0 + (j)];  Q0 = __builtin_elementwise_fma(xe2[0 + (j)],  xe2[0 + (j)],  Q0); \
        S1 += xe2[8 + (j)];  Q1 = __builtin_elementwise_fma(xe2[8 + (j)],  xe2[8 + (j)],  Q1); \
        S2 += xe2[16 + (j)]; Q2 = __builtin_elementwise_fma(xe2[16 + (j)], xe2[16 + (j)], Q2); \
        S3 += xe2[24 + (j)]; Q3 = __builtin_elementwise_fma(xe2[24 + (j)], xe2[24 + (j)], Q3); }
        LNE(1) LNE(2) LNE(3) LNE(4) LNE(5) LNE(6) LNE(7)
        f2 Sab = S0 + S1, Scd = S2 + S3;
        f2 Qab = Q0 + Q1, Qcd = Q2 + Q3;
        f2 St = Sab + Scd, Qt = Qab + Qcd;
        float mean = (St.x + St.y) * (1.0f / HID);
        float ms   = (Qt.x + Qt.y) * (1.0f / HID);
        float var  = fmaf(-mean, mean, ms);                 // E[x^2] - mean^2
        float rstd = __builtin_amdgcn_rsqf(var + 1e-6f);

        // ---- affine-folded scale/shift + GELU (packed sigmoid tail) ----
        {
            const f2 rs2  = {rstd, rstd};
            const f2 mn2n = {-mean, -mean};
            const f2 kBC2 = {kBCl, kBCl};
            const f2 kC2n = {kCl, kCl};
            const f2 one2 = {1.0f, 1.0f};
#define GEL1(p, lsS, lbS) { \
            f2 a = (lsS) * rs2; \
            f2 b = __builtin_elementwise_fma(mn2n, a, (lbS)); \
            f2 g = __builtin_elementwise_fma(xe2[p], a, b); \
            f2 g2 = g * g; \
            f2 inner = __builtin_elementwise_fma(g2, kBC2, kC2n); \
            f2 z = g * inner; \
            f2 e = {__builtin_amdgcn_exp2f(z.x), __builtin_amdgcn_exp2f(z.y)}; \
            f2 d = one2 + e; \
            f2 r = {__builtin_amdgcn_rcpf(d.x), __builtin_amdgcn_rcpf(d.y)}; \
            xe2[p] = g * r; }
#define GELT(W, pb) \
            GEL1((pb)+0, PKW(W,0), PKW(W,1)) \
            GEL1((pb)+1, PKW(W,2), PKW(W,3)) \
            GEL1((pb)+2, PKW(W,4), PKW(W,5)) \
            GEL1((pb)+3, PKW(W,6), PKW(W,7))
#define GELG(h) { f16s wa, wb, wc, wd; \
            SLOAD4(wa, wb, wc, wd, lsb, (h)*256, (h)*256+64, (h)*256+128, (h)*256+192) \
            GELT(wa, 16*(h)+0) GELT(wb, 16*(h)+4) \
            GELT(wc, 16*(h)+8) GELT(wd, 16*(h)+12) }
            GELG(0) GELG(1)
        }

        // ---- out matmul packed, 4 partial accs (8-deep) + tree combine ----
        float u[SD];
#define OUTI(i) { f16s wa, wb, wc, wd; \
        SLOAD4(wa, wb, wc, wd, owt, (i)*256, (i)*256+64, (i)*256+128, (i)*256+192) \
        f2 a0 = {0.f, 0.f}, a1 = {0.f, 0.f}, a2 = {0.f, 0.f}, a3 = {0.f, 0.f}; \
        AP8(OPK_E, a0, 0,  wa) AP8(OPK_E, a1, 8,  wb) \
        AP8(OPK_E, a2, 16, wc) AP8(OPK_E, a3, 24, wd) \
        f2 aab = a0 + a1, acd = a2 + a3; \
        f2 at = aab + acd; \
        u[i] = (at.x + at.y) + obv[i]; }
        REP7(OUTI)

        // ---- L2 normalize, 2-chain square-sum ----
        float ss0 = u[0] * u[0], ss1 = u[1] * u[1];
        ss0 = fmaf(u[2], u[2], ss0); ss1 = fmaf(u[3], u[3], ss1);
        ss0 = fmaf(u[4], u[4], ss0); ss1 = fmaf(u[5], u[5], ss1);
        ss0 = fmaf(u[6], u[6], ss0);
        float ss = ss0 + ss1;
        float inv = __fdividef(1.0f, __builtin_amdgcn_sqrtf(ss) + 1e-8f);

        // ---- damped update + convergence, 2-chain dd ----
        float un0, mn0;
        float dd0 = 0.f, dd1 = 0.f;
#define UPD2(i, ddx) { float un = u[i] * inv; float mn = 0.5f * mu[i] + 0.5f * un; \
        float d = mn - mu[i]; ddx = fmaf(d, d, ddx); mu[i] = mn; }
        UPD2(0, dd0) UPD2(1, dd1) UPD2(2, dd0) UPD2(3, dd1)
        UPD2(4, dd0) UPD2(5, dd1) UPD2(6, dd0)
        float dd = dd0 + dd1;
        if (sqrtf(dd) < 1e-4f) conv = 1.0f;
    }

#define ST(i) out_mu[(size_t)row * SD + (i)] = mu[i];
    REP7(ST)
    out_cv[row] = conv;
}

extern "C" void kernel_launch(void* const* d_in, const int* in_sizes, int n_in,
                              void* d_out, int out_size, void* d_ws, size_t ws_size,
                              hipStream_t stream) {
    const float* s7  = (const float*)d_in[0];
    const float* w0  = (const float*)d_in[1];
    const float* b0  = (const float*)d_in[2];
    const float* lns = (const float*)d_in[3];
    const float* lnb = (const float*)d_in[4];
    const float* ow  = (const float*)d_in[5];
    const float* ob  = (const float*)d_in[6];
    const int Bn = in_sizes[0] / SD;

    float* out_mu = (float*)d_out;
    float* out_cv = out_mu + (size_t)Bn * SD;
    float* ws     = (float*)d_ws;            // owt[448] | lsbI[128]
    float* owt    = ws;
    float* lsb    = ws + HID * SD;

    hipLaunchKernelGGL(prep_kernel, dim3(1), dim3(640), 0, stream, ow, lns, lnb, ws);

    const int block = 256;
    const int grid  = (Bn + block - 1) / block;
    hipLaunchKernelGGL(strange_loop_kernel, dim3(grid), dim3(block), 0, stream,
                       s7, w0, b0, owt, lsb, ob, out_mu, out_cv, Bn);
}